// Round 2
// baseline (361.269 us; speedup 1.0000x reference)
//
#include <hip/hip_runtime.h>

#define TEN 10

// ---------------------------------------------------------------------------
// Phase A: 5 lanes per chunk-GROUP, COLUMN ownership, TWO chunks per group.
// Lane sub owns columns j0=2*sub, j1=2*sub+1 of W and M for BOTH chunks.
// The P-slice p[c][k][a] = P[k][a][j] (200 floats) is SHARED by the two
// streams -> live state ~330 regs, fits the 512-reg unified file at
// 1 wave/SIMD (r1 showed 2 HW waves/SIMD forces a 256-reg budget -> scratch
// spill, WRITE_SIZE 7.9 MB, dur 240us). Software TLP instead: streams A and
// B are independent between barriers, so B's 200 W-build FMAs hide A's
// ~300-cycle LDS read latency and vice versa (the 1280 cyc/step stall that
// single-stream 1-wave execution exposed).
// LDS: A-slots [48][132] @0, B-slots [48][132] @6336 (same stride-132 ->
// group bases spread over 8 bank offsets, <=2-way = free per m136).
// No __syncthreads in the main loop: sharing is intra-wave (in-order DS
// pipe); wave_barrier() pins program order of DS ops.
// After the loop each group folds M_A @ M_B in-lane -> 48 tree leaves.
// 96 chunks/block, grid=256 (1 block/CU), C = 24576, Lc ~ 85/86 (tails).
// ---------------------------------------------------------------------------

#define PUBLISH(mREG, slot)                                                     \
    {                                                                           \
        float* c0_ = (slot) + j0 * 12;                                          \
        reinterpret_cast<float4*>(c0_)[0] = make_float4(mREG[0][0], mREG[1][0], mREG[2][0], mREG[3][0]); \
        reinterpret_cast<float4*>(c0_)[1] = make_float4(mREG[4][0], mREG[5][0], mREG[6][0], mREG[7][0]); \
        reinterpret_cast<float2*>(c0_ + 8)[0] = make_float2(mREG[8][0], mREG[9][0]); \
        float* c1_ = (slot) + j1 * 12;                                          \
        reinterpret_cast<float4*>(c1_)[0] = make_float4(mREG[0][1], mREG[1][1], mREG[2][1], mREG[3][1]); \
        reinterpret_cast<float4*>(c1_)[1] = make_float4(mREG[4][1], mREG[5][1], mREG[6][1], mREG[7][1]); \
        reinterpret_cast<float2*>(c1_ + 8)[0] = make_float2(mREG[8][1], mREG[9][1]); \
    }

#define WBUILD(xv, w0, w1)                                                      \
    _Pragma("unroll")                                                           \
    for (int a = 0; a < TEN; ++a) {                                             \
        float a0_ = (xv)[0] * p[0][0][a];                                       \
        float a1_ = (xv)[0] * p[1][0][a];                                       \
        _Pragma("unroll")                                                       \
        for (int k = 1; k < TEN; ++k) {                                         \
            a0_ = fmaf((xv)[k], p[0][k][a], a0_);                               \
            a1_ = fmaf((xv)[k], p[1][k][a], a1_);                               \
        }                                                                       \
        (w0)[a] = a0_; (w1)[a] = a1_;                                           \
    }

// M_new[:,own] = M_t @ W[:,own], streamed from LDS, accumulated in-place
// (mREG regs are dead after PUBLISH: old M lives in LDS). a==0 term is a
// mul -> no zero-init.
#define STREAM(slot, w0, w1, mREG)                                              \
    _Pragma("unroll")                                                           \
    for (int a = 0; a < TEN; ++a) {                                             \
        const float4 v0_ = reinterpret_cast<const float4*>((slot) + a * 12)[0]; \
        const float4 v1_ = reinterpret_cast<const float4*>((slot) + a * 12)[1]; \
        const float2 v2_ = reinterpret_cast<const float2*>((slot) + a * 12 + 8)[0]; \
        const float ca_[TEN] = {v0_.x, v0_.y, v0_.z, v0_.w, v1_.x, v1_.y, v1_.z, v1_.w, v2_.x, v2_.y}; \
        const float wa0_ = (w0)[a], wa1_ = (w1)[a];                             \
        if (a == 0) {                                                           \
            _Pragma("unroll")                                                   \
            for (int r = 0; r < TEN; ++r) { mREG[r][0] = ca_[r] * wa0_; mREG[r][1] = ca_[r] * wa1_; } \
        } else {                                                                \
            _Pragma("unroll")                                                   \
            for (int r = 0; r < TEN; ++r) { mREG[r][0] = fmaf(ca_[r], wa0_, mREG[r][0]); mREG[r][1] = fmaf(ca_[r], wa1_, mREG[r][1]); } \
        }                                                                       \
    }

__global__ __attribute__((amdgpu_flat_work_group_size(256, 256),
                          amdgpu_waves_per_eu(1, 1)))
void automaton_chunks(const float* __restrict__ x, const float* __restrict__ P,
                      float* __restrict__ outBlk, long long T, int C)
{
    // main loop: A-slots 48*132 @0, B-slots 48*132 @6336 -> 12672 floats.
    // tree: T0 = 48*120 @0, T1 @5760 (extent 8640) -> overlaps, fine.
    __shared__ __align__(16) float lds[12672];

    const int tid  = threadIdx.x;
    const int wave = tid >> 6;
    const int lane = tid & 63;
    const int grp  = lane / 5;        // 0..11 active, 12 => idle lanes 60..63
    const int sub  = lane % 5;
    const bool active = (grp < 12);
    const int gib  = wave * 12 + grp; // group within block 0..47
    const int j0 = 2 * sub, j1 = j0 + 1;

    float p[2][TEN][TEN];             // p[c][k][a] = P[k][a][2sub+c]  (shared A/B)
    float mA[TEN][2], mB[TEN][2];     // own columns of M for chunks A, B
    long long LA = 0, LB = 0;
    const float2 *xpA = nullptr, *xpB = nullptr;
    float* slotA = lds + (active ? gib : 0) * 132;
    float* slotB = slotA + 6336;

    if (active) {
        const long long cA  = (long long)blockIdx.x * 96 + 2 * gib;
        const long long sA0 = cA * T / C;
        const long long sA1 = (cA + 1) * T / C;
        const long long sB1 = (cA + 2) * T / C;
        LA = sA1 - sA0;
        LB = sB1 - sA1;
        xpA = reinterpret_cast<const float2*>(x) + sA0 * 5;
        xpB = reinterpret_cast<const float2*>(x) + sA1 * 5;
#pragma unroll
        for (int k = 0; k < TEN; ++k)
#pragma unroll
            for (int a = 0; a < TEN; ++a) {
                const float2 v = *reinterpret_cast<const float2*>(P + k * 100 + a * TEN + j0);
                p[0][k][a] = v.x;
                p[1][k][a] = v.y;
            }
#pragma unroll
        for (int r = 0; r < TEN; ++r) {
            mA[r][0] = (r == j0) ? 1.0f : 0.0f;
            mA[r][1] = (r == j1) ? 1.0f : 0.0f;
            mB[r][0] = mA[r][0];
            mB[r][1] = mA[r][1];
        }
    }

    float2 nA0, nA1, nA2, nA3, nA4, nB0, nB1, nB2, nB3, nB4;
    if (active) {
        nA0 = xpA[0]; nA1 = xpA[1]; nA2 = xpA[2]; nA3 = xpA[3]; nA4 = xpA[4]; xpA += 5;
        nB0 = xpB[0]; nB1 = xpB[1]; nB2 = xpB[2]; nB3 = xpB[3]; nB4 = xpB[4]; xpB += 5;
    }

    if (active) {
        const long long smin = (LA < LB) ? LA : LB;
#pragma unroll 1
        for (long long s = 0; s < smin; ++s) {
            const float xvA[TEN] = {nA0.x, nA0.y, nA1.x, nA1.y, nA2.x,
                                    nA2.y, nA3.x, nA3.y, nA4.x, nA4.y};
            const float xvB[TEN] = {nB0.x, nB0.y, nB1.x, nB1.y, nB2.x,
                                    nB2.y, nB3.x, nB3.y, nB4.x, nB4.y};
            if (s + 1 < LA) {
                nA0 = xpA[0]; nA1 = xpA[1]; nA2 = xpA[2]; nA3 = xpA[3]; nA4 = xpA[4];
                xpA += 5;
            }
            if (s + 1 < LB) {
                nB0 = xpB[0]; nB1 = xpB[1]; nB2 = xpB[2]; nB3 = xpB[3]; nB4 = xpB[4];
                xpB += 5;
            }

            PUBLISH(mA, slotA)
            PUBLISH(mB, slotB)
            __builtin_amdgcn_wave_barrier();   // writes -> reads order

            float wA0[TEN], wA1[TEN], wB0[TEN], wB1[TEN];
            WBUILD(xvA, wA0, wA1)
            WBUILD(xvB, wB0, wB1)

            STREAM(slotA, wA0, wA1, mA)
            STREAM(slotB, wB0, wB1, mB)
            __builtin_amdgcn_wave_barrier();   // reads before next step's writes
        }

        // tails: chunk lengths differ by at most 1
        if (LA > smin) {
            const float xvA[TEN] = {nA0.x, nA0.y, nA1.x, nA1.y, nA2.x,
                                    nA2.y, nA3.x, nA3.y, nA4.x, nA4.y};
            PUBLISH(mA, slotA)
            __builtin_amdgcn_wave_barrier();
            float wA0[TEN], wA1[TEN];
            WBUILD(xvA, wA0, wA1)
            STREAM(slotA, wA0, wA1, mA)
            __builtin_amdgcn_wave_barrier();
        }
        if (LB > smin) {
            const float xvB[TEN] = {nB0.x, nB0.y, nB1.x, nB1.y, nB2.x,
                                    nB2.y, nB3.x, nB3.y, nB4.x, nB4.y};
            PUBLISH(mB, slotB)
            __builtin_amdgcn_wave_barrier();
            float wB0[TEN], wB1[TEN];
            WBUILD(xvB, wB0, wB1)
            STREAM(slotB, wB0, wB1, mB)
            __builtin_amdgcn_wave_barrier();
        }

        // group fold: mA <- M_A @ M_B  (weights are mB's own columns)
        {
            PUBLISH(mA, slotA)
            __builtin_amdgcn_wave_barrier();
            float wA0[TEN], wA1[TEN];
#pragma unroll
            for (int a = 0; a < TEN; ++a) { wA0[a] = mB[a][0]; wA1[a] = mB[a][1]; }
            STREAM(slotA, wA0, wA1, mA)
        }
    }

    // ---- in-block ordered tree: 48 group matrices -> 1 --------------------
    __syncthreads();                  // main-loop LDS region now dead
    if (active) {
        // stage own columns into ROW-major tree slot gib (stride 120, rows 12)
        float* t = lds + gib * 120;
#pragma unroll
        for (int r = 0; r < TEN; ++r) {
            t[r * 12 + j0] = mA[r][0];
            t[r * 12 + j1] = mA[r][1];
        }
    }
    __syncthreads();

    // thread-per-row tree products: 48 -> 24 -> 12 -> 6 -> 3 (ping-pong)
    {
        const float* src = lds;
        float* dst = lds + 5760;
        int n = 48;
        while (n > 3) {
            const int np = n >> 1;
            const int pI = tid / TEN;
            const int r  = tid % TEN;
            if (pI < np) {
                const float* A = src + (2 * pI) * 120;
                const float* B = src + (2 * pI + 1) * 120;
                float ar[TEN];
#pragma unroll
                for (int j = 0; j < TEN; ++j) ar[j] = A[r * 12 + j];
                float c[TEN] = {0, 0, 0, 0, 0, 0, 0, 0, 0, 0};
#pragma unroll
                for (int a = 0; a < TEN; ++a) {
                    const float ma = ar[a];
#pragma unroll
                    for (int j = 0; j < TEN; ++j) c[j] = fmaf(ma, B[a * 12 + j], c[j]);
                }
                float* Cp = dst + pI * 120;
#pragma unroll
                for (int j = 0; j < TEN; ++j) Cp[r * 12 + j] = c[j];
            }
            __syncthreads();
            const float* ts = src; src = dst; dst = const_cast<float*>(ts);
            n = np;
        }
        // 3 matrices left in src (== lds). Serial: (M0*M1)*M2 by 10 threads.
        if (tid < TEN) {
            const int r = tid;
            float ar[TEN];
#pragma unroll
            for (int j = 0; j < TEN; ++j) ar[j] = src[r * 12 + j];
            float c[TEN] = {0, 0, 0, 0, 0, 0, 0, 0, 0, 0};
#pragma unroll
            for (int a = 0; a < TEN; ++a) {
                const float ma = ar[a];
#pragma unroll
                for (int j = 0; j < TEN; ++j) c[j] = fmaf(ma, src[120 + a * 12 + j], c[j]);
            }
#pragma unroll
            for (int j = 0; j < TEN; ++j) lds[5760 + r * 12 + j] = c[j];
        }
        __syncthreads();
        if (tid < TEN) {
            const int r = tid;
            float c[TEN] = {0, 0, 0, 0, 0, 0, 0, 0, 0, 0};
#pragma unroll
            for (int a = 0; a < TEN; ++a) {
                const float ma = lds[5760 + r * 12 + a];
#pragma unroll
                for (int j = 0; j < TEN; ++j) c[j] = fmaf(ma, src[240 + a * 12 + j], c[j]);
            }
            float* dr = outBlk + (size_t)blockIdx.x * 100 + r * TEN;
#pragma unroll
            for (int j = 0; j < TEN; ++j) dr[j] = c[j];
        }
    }
}

// ---------------------------------------------------------------------------
// tree64 helper for the final kernel (row-major slots, stride 120).
// Quad row partition {0,1,2},{3,4,5},{6,7,(dup)},{8,9,(dup)}.
// ---------------------------------------------------------------------------
__device__ __forceinline__ void tree64(float* lds, int tid)
{
    const int q     = tid >> 2;
    const int sub   = tid & 3;
    const int rbase = (sub == 3) ? 8 : sub * 3;
    const int r0 = rbase, r1 = rbase + 1;
    const int r2 = (rbase + 2 > 9) ? 9 : rbase + 2;
    const bool w2 = (sub < 2);

    for (int np = 32; np >= 1; np >>= 1) {
        float c[3][TEN];
        if (q < np) {
            const float* A = lds + (2 * q) * 120;
            const float* B = lds + (2 * q + 1) * 120;
            float ar[3][TEN];
#pragma unroll
            for (int t = 0; t < 3; ++t) {
                const int rt = (t == 0) ? r0 : (t == 1) ? r1 : r2;
                const float4 a0 = reinterpret_cast<const float4*>(A + rt * 12)[0];
                const float4 a1 = reinterpret_cast<const float4*>(A + rt * 12)[1];
                const float2 a2 = reinterpret_cast<const float2*>(A + rt * 12 + 8)[0];
                ar[t][0]=a0.x; ar[t][1]=a0.y; ar[t][2]=a0.z; ar[t][3]=a0.w;
                ar[t][4]=a1.x; ar[t][5]=a1.y; ar[t][6]=a1.z; ar[t][7]=a1.w;
                ar[t][8]=a2.x; ar[t][9]=a2.y;
#pragma unroll
                for (int j = 0; j < TEN; ++j) c[t][j] = 0.0f;
            }
#pragma unroll
            for (int a = 0; a < TEN; ++a) {
                const float4 b0 = reinterpret_cast<const float4*>(B + a * 12)[0];
                const float4 b1 = reinterpret_cast<const float4*>(B + a * 12)[1];
                const float2 b2 = reinterpret_cast<const float2*>(B + a * 12 + 8)[0];
                const float br[TEN] = {b0.x,b0.y,b0.z,b0.w,b1.x,b1.y,b1.z,b1.w,b2.x,b2.y};
#pragma unroll
                for (int t = 0; t < 3; ++t) {
                    const float ma = ar[t][a];
#pragma unroll
                    for (int j = 0; j < TEN; ++j) c[t][j] = fmaf(ma, br[j], c[t][j]);
                }
            }
        }
        __syncthreads();
        if (q < np) {
            float* C = lds + q * 120;
#pragma unroll
            for (int t = 0; t < 3; ++t) {
                const int rt = (t == 0) ? r0 : (t == 1) ? r1 : r2;
                if (t < 2 || w2) {
                    float* cr = C + rt * 12;
                    reinterpret_cast<float4*>(cr)[0] = make_float4(c[t][0], c[t][1], c[t][2], c[t][3]);
                    reinterpret_cast<float4*>(cr)[1] = make_float4(c[t][4], c[t][5], c[t][6], c[t][7]);
                    reinterpret_cast<float2*>(cr + 8)[0] = make_float2(c[t][8], c[t][9]);
                }
            }
        }
        __syncthreads();
    }
}

// ---------------------------------------------------------------------------
// Final: one block. 64 quads chain 4 consecutive block-matrices (256 -> 64),
// tree64 -> 1, then apply start/accept.
// ---------------------------------------------------------------------------
__global__ void automaton_final(const float* __restrict__ blkM,
                                const float* __restrict__ start,
                                const float* __restrict__ acc,
                                float* __restrict__ outv)
{
    __shared__ __align__(16) float lds[7680];
    __shared__ float sv[TEN];
    const int tid = threadIdx.x;
    const int q   = tid >> 2;
    const int sub = tid & 3;
    const int rbase = (sub == 3) ? 8 : sub * 3;
    const int rr0 = rbase, rr1 = rbase + 1;
    const int rr2 = (rbase + 2 > 9) ? 9 : rbase + 2;
    const bool w2 = (sub < 2);

    float a[3][TEN];
    {
        const int rr[3] = {rr0, rr1, rr2};
        const float* A0 = blkM + (size_t)(4 * q) * 100;
#pragma unroll
        for (int t = 0; t < 3; ++t) {
            const float2* pp = reinterpret_cast<const float2*>(A0 + rr[t] * TEN);
            const float2 a0 = pp[0], a1 = pp[1], a2 = pp[2], a3 = pp[3], a4 = pp[4];
            a[t][0]=a0.x; a[t][1]=a0.y; a[t][2]=a1.x; a[t][3]=a1.y; a[t][4]=a2.x;
            a[t][5]=a2.y; a[t][6]=a3.x; a[t][7]=a3.y; a[t][8]=a4.x; a[t][9]=a4.y;
        }
    }
#pragma unroll 1
    for (int i = 1; i < 4; ++i) {
        const float* B = blkM + (size_t)(4 * q + i) * 100;
        float c[3][TEN];
#pragma unroll
        for (int t = 0; t < 3; ++t)
#pragma unroll
            for (int j = 0; j < TEN; ++j) c[t][j] = 0.0f;
#pragma unroll
        for (int aa = 0; aa < TEN; ++aa) {
            const float2* br = reinterpret_cast<const float2*>(B + aa * TEN);
            const float2 b0 = br[0], b1 = br[1], b2 = br[2], b3 = br[3], b4 = br[4];
            const float bv[TEN] = {b0.x,b0.y,b1.x,b1.y,b2.x,b2.y,b3.x,b3.y,b4.x,b4.y};
#pragma unroll
            for (int t = 0; t < 3; ++t) {
                const float ma = a[t][aa];
#pragma unroll
                for (int j = 0; j < TEN; ++j) c[t][j] = fmaf(ma, bv[j], c[t][j]);
            }
        }
#pragma unroll
        for (int t = 0; t < 3; ++t)
#pragma unroll
            for (int j = 0; j < TEN; ++j) a[t][j] = c[t][j];
    }
    {
        float* dst = lds + q * 120;
#pragma unroll
        for (int t = 0; t < 3; ++t) {
            const int rt = (t == 0) ? rr0 : (t == 1) ? rr1 : rr2;
            if (t < 2 || w2) {
                float* dr = dst + rt * 12;
                reinterpret_cast<float4*>(dr)[0] = make_float4(a[t][0], a[t][1], a[t][2], a[t][3]);
                reinterpret_cast<float4*>(dr)[1] = make_float4(a[t][4], a[t][5], a[t][6], a[t][7]);
                reinterpret_cast<float2*>(dr + 8)[0] = make_float2(a[t][8], a[t][9]);
            }
        }
    }
    __syncthreads();
    tree64(lds, tid);

    if (tid < TEN) {
        const int j = tid;
        float v = 0.0f;
#pragma unroll
        for (int r = 0; r < TEN; ++r) v = fmaf(start[r], lds[r * 12 + j], v);
        sv[j] = v;
    }
    __syncthreads();
    if (tid == 0) {
        float o0 = 0.0f, o1 = 0.0f;
#pragma unroll
        for (int j = 0; j < TEN; ++j) {
            o0 = fmaf(sv[j], acc[2 * j + 0], o0);
            o1 = fmaf(sv[j], acc[2 * j + 1], o1);
        }
        outv[0] = o0;
        outv[1] = o1;
    }
}

extern "C" void kernel_launch(void* const* d_in, const int* in_sizes, int n_in,
                              void* d_out, int out_size, void* d_ws, size_t ws_size,
                              hipStream_t stream)
{
    const float* x     = (const float*)d_in[0];
    const float* P     = (const float*)d_in[1];
    const float* start = (const float*)d_in[2];
    const float* acc   = (const float*)d_in[3];
    float* out         = (float*)d_out;

    const long long T = (long long)in_sizes[0] / TEN;  // 2,097,152 steps
    const int C = 24576;                               // 96 chunks x 256 blocks

    float* blkM = (float*)d_ws;                        // [256][10][10]

    automaton_chunks<<<256, 256, 0, stream>>>(x, P, blkM, T, C);
    automaton_final<<<1, 256, 0, stream>>>(blkM, start, acc, out);
}

// Round 3
// 304.963 us; speedup vs baseline: 1.1846x; 1.1846x over previous
//
#include <hip/hip_runtime.h>

#define TEN 10

// ---------------------------------------------------------------------------
// Phase A: 5 lanes per chunk, ROW ownership of M + COLUMN build of W.
// Lane sub keeps rows r0=2*sub, r1=2*sub+1 of M in REGISTERS (never shared)
// and builds columns j0=2*sub, j1=2*sub+1 of W_t (P-slice p[c][k][a] =
// P[k][a][2sub+c], 200 floats, same as before).
// The LDS-shared operand is W (NOT M). W_t depends only on x -> it is built
// and published ONE STEP AHEAD into a double buffer, so the DS write->read
// gap is a whole iteration (~800 cyc) and the UPDATE's 30 column reads are
// independent of all preceding VALU (the next step's W-build) -> read
// latency hides under 400 FMA cycles. The serial recurrence m->m is a pure
// register FMA chain (20 independent 10-deep dots).
// r1/r2 lesson: 2 HW waves (256-reg budget) scratch-spills the P-slice;
// 2 SW streams (~330 live) drowns in accvgpr moves. This keeps the baseline
// live-set and instruction mix; only the dependency graph changes.
// LDS: W col-major, col stride 12 (every column 16B-aligned -> b128/b64),
// slot stride 132 (<=2-way bank alias across groups = free), buf B at +6336.
// One wave_barrier per iteration: reads touch buf cur, writes buf cur^1
// (disjoint), cross-iteration hazards separated by the barrier.
// 12 chunks/wave, 48/block, grid=256 (1 block/CU, 1 wave/SIMD), C=12288.
// ---------------------------------------------------------------------------

#define WBUILD(xv, w0, w1)                                                      \
    _Pragma("unroll")                                                           \
    for (int a = 0; a < TEN; ++a) {                                             \
        float a0_ = (xv)[0] * p[0][0][a];                                       \
        float a1_ = (xv)[0] * p[1][0][a];                                       \
        _Pragma("unroll")                                                       \
        for (int k = 1; k < TEN; ++k) {                                         \
            a0_ = fmaf((xv)[k], p[0][k][a], a0_);                               \
            a1_ = fmaf((xv)[k], p[1][k][a], a1_);                               \
        }                                                                       \
        (w0)[a] = a0_; (w1)[a] = a1_;                                           \
    }

#define PUBLISH_W(w0, w1, slot)                                                 \
    {                                                                           \
        float* c0_ = (slot) + j0 * 12;                                          \
        reinterpret_cast<float4*>(c0_)[0] = make_float4((w0)[0], (w0)[1], (w0)[2], (w0)[3]); \
        reinterpret_cast<float4*>(c0_)[1] = make_float4((w0)[4], (w0)[5], (w0)[6], (w0)[7]); \
        reinterpret_cast<float2*>(c0_ + 8)[0] = make_float2((w0)[8], (w0)[9]);  \
        float* c1_ = (slot) + j1 * 12;                                          \
        reinterpret_cast<float4*>(c1_)[0] = make_float4((w1)[0], (w1)[1], (w1)[2], (w1)[3]); \
        reinterpret_cast<float4*>(c1_)[1] = make_float4((w1)[4], (w1)[5], (w1)[6], (w1)[7]); \
        reinterpret_cast<float2*>(c1_ + 8)[0] = make_float2((w1)[8], (w1)[9]);  \
    }

// m_new[rc][j] = sum_a m[rc][a] * W[a][j] : read column j of W_s (broadcast
// within the 5-lane group), two 10-deep dots per j. a-order 0..9 keeps the
// summation order identical to the previous kernel (bit-exact).
#define UPDATE(slot)                                                            \
    {                                                                           \
        float mn0[TEN], mn1[TEN];                                              \
        _Pragma("unroll")                                                       \
        for (int j = 0; j < TEN; ++j) {                                         \
            const float4 v0_ = reinterpret_cast<const float4*>((slot) + j * 12)[0]; \
            const float4 v1_ = reinterpret_cast<const float4*>((slot) + j * 12)[1]; \
            const float2 v2_ = reinterpret_cast<const float2*>((slot) + j * 12 + 8)[0]; \
            const float ca_[TEN] = {v0_.x, v0_.y, v0_.z, v0_.w, v1_.x, v1_.y, v1_.z, v1_.w, v2_.x, v2_.y}; \
            float t0_ = m0[0] * ca_[0];                                         \
            float t1_ = m1[0] * ca_[0];                                         \
            _Pragma("unroll")                                                   \
            for (int a = 1; a < TEN; ++a) {                                     \
                t0_ = fmaf(m0[a], ca_[a], t0_);                                 \
                t1_ = fmaf(m1[a], ca_[a], t1_);                                 \
            }                                                                   \
            mn0[j] = t0_; mn1[j] = t1_;                                         \
        }                                                                       \
        _Pragma("unroll")                                                       \
        for (int j = 0; j < TEN; ++j) { m0[j] = mn0[j]; m1[j] = mn1[j]; }       \
    }

__global__ __attribute__((amdgpu_flat_work_group_size(256, 256),
                          amdgpu_waves_per_eu(1, 1)))
void automaton_chunks(const float* __restrict__ x, const float* __restrict__ P,
                      float* __restrict__ outBlk, long long T, int C)
{
    // main loop: W buf0 48*132 @0, buf1 @6336 -> 12672 floats.
    // tree: T0 = 48*120 @0, T1 @5760 (extent 8640) -> reuses, fine.
    __shared__ __align__(16) float lds[12672];

    const int tid  = threadIdx.x;
    const int wave = tid >> 6;
    const int lane = tid & 63;
    const int grp  = lane / 5;        // 0..11 active, 12 => idle lanes 60..63
    const int sub  = lane % 5;
    const bool active = (grp < 12);
    const int gib  = wave * 12 + grp; // chunk within block 0..47
    const int j0 = 2 * sub, j1 = j0 + 1;

    float p[2][TEN][TEN];             // p[c][k][a] = P[k][a][2sub+c]
    float m0[TEN], m1[TEN];           // OWN ROWS j0, j1 of M (registers only)
    long long Lc = 0;
    const float2* xp = nullptr;
    float* slotA = lds + (active ? gib : 0) * 132;  // W buffer 0
    float* slotB = slotA + 6336;                    // W buffer 1

    if (active) {
        const long long chunk = (long long)blockIdx.x * 48 + gib;
        const long long s0 = chunk * T / C;
        const long long s1 = (chunk + 1) * T / C;
        Lc = s1 - s0;
        xp = reinterpret_cast<const float2*>(x) + s0 * 5;
#pragma unroll
        for (int k = 0; k < TEN; ++k)
#pragma unroll
            for (int a = 0; a < TEN; ++a) {
                const float2 v = *reinterpret_cast<const float2*>(P + k * 100 + a * TEN + j0);
                p[0][k][a] = v.x;
                p[1][k][a] = v.y;
            }
#pragma unroll
        for (int j = 0; j < TEN; ++j) {
            m0[j] = (j == j0) ? 1.0f : 0.0f;
            m1[j] = (j == j1) ? 1.0f : 0.0f;
        }
    }

    if (active) {
        float2 nx0 = xp[0], nx1 = xp[1], nx2 = xp[2], nx3 = xp[3], nx4 = xp[4];
        xp += 5;

        // prologue: build W_0 from x_0, publish to buf A; prefetch x_1
        {
            const float xv[TEN] = {nx0.x, nx0.y, nx1.x, nx1.y, nx2.x,
                                   nx2.y, nx3.x, nx3.y, nx4.x, nx4.y};
            if (Lc > 1) {
                nx0 = xp[0]; nx1 = xp[1]; nx2 = xp[2]; nx3 = xp[3]; nx4 = xp[4];
                xp += 5;
            }
            float w0[TEN], w1[TEN];
            WBUILD(xv, w0, w1)
            PUBLISH_W(w0, w1, slotA)
        }
        __builtin_amdgcn_wave_barrier();

        float* cur = slotA;
        float* nxt = slotB;
#pragma unroll 1
        for (long long s = 0; s < Lc; ++s) {
            const bool more = (s + 1 < Lc);   // chunk-uniform within the group
            float w0[TEN], w1[TEN];
            if (more) {
                // W_{s+1} from x_{s+1} (in nx); prefetch x_{s+2}
                const float xv[TEN] = {nx0.x, nx0.y, nx1.x, nx1.y, nx2.x,
                                       nx2.y, nx3.x, nx3.y, nx4.x, nx4.y};
                if (s + 2 < Lc) {
                    nx0 = xp[0]; nx1 = xp[1]; nx2 = xp[2]; nx3 = xp[3]; nx4 = xp[4];
                    xp += 5;
                }
                WBUILD(xv, w0, w1)
            }
            // consume W_s from cur (published >=1 iteration ago; its loads are
            // independent of WBUILD above -> hoistable, latency hidden)
            UPDATE(cur)
            if (more) PUBLISH_W(w0, w1, nxt)
            __builtin_amdgcn_wave_barrier();   // separates cross-iteration RAW/WAR
            float* t = cur; cur = nxt; nxt = t;
        }
    }

    // ---- in-block ordered tree: 48 chunk matrices -> 1 --------------------
    __syncthreads();                  // main-loop LDS region now dead
    if (active) {
        // stage own ROWS into ROW-major tree slot gib (stride 120, rows 12)
        float* t = lds + gib * 120;
        float* r0p = t + j0 * 12;
        reinterpret_cast<float4*>(r0p)[0] = make_float4(m0[0], m0[1], m0[2], m0[3]);
        reinterpret_cast<float4*>(r0p)[1] = make_float4(m0[4], m0[5], m0[6], m0[7]);
        reinterpret_cast<float2*>(r0p + 8)[0] = make_float2(m0[8], m0[9]);
        float* r1p = t + j1 * 12;
        reinterpret_cast<float4*>(r1p)[0] = make_float4(m1[0], m1[1], m1[2], m1[3]);
        reinterpret_cast<float4*>(r1p)[1] = make_float4(m1[4], m1[5], m1[6], m1[7]);
        reinterpret_cast<float2*>(r1p + 8)[0] = make_float2(m1[8], m1[9]);
    }
    __syncthreads();

    // thread-per-row tree products: 48 -> 24 -> 12 -> 6 -> 3 (ping-pong)
    {
        const float* src = lds;
        float* dst = lds + 5760;
        int n = 48;
        while (n > 3) {
            const int np = n >> 1;
            const int pI = tid / TEN;
            const int r  = tid % TEN;
            if (pI < np) {
                const float* A = src + (2 * pI) * 120;
                const float* B = src + (2 * pI + 1) * 120;
                float ar[TEN];
#pragma unroll
                for (int j = 0; j < TEN; ++j) ar[j] = A[r * 12 + j];
                float c[TEN] = {0, 0, 0, 0, 0, 0, 0, 0, 0, 0};
#pragma unroll
                for (int a = 0; a < TEN; ++a) {
                    const float ma = ar[a];
#pragma unroll
                    for (int j = 0; j < TEN; ++j) c[j] = fmaf(ma, B[a * 12 + j], c[j]);
                }
                float* Cp = dst + pI * 120;
#pragma unroll
                for (int j = 0; j < TEN; ++j) Cp[r * 12 + j] = c[j];
            }
            __syncthreads();
            const float* ts = src; src = dst; dst = const_cast<float*>(ts);
            n = np;
        }
        // 3 matrices left in src (== lds). Serial: (M0*M1)*M2 by 10 threads.
        if (tid < TEN) {
            const int r = tid;
            float ar[TEN];
#pragma unroll
            for (int j = 0; j < TEN; ++j) ar[j] = src[r * 12 + j];
            float c[TEN] = {0, 0, 0, 0, 0, 0, 0, 0, 0, 0};
#pragma unroll
            for (int a = 0; a < TEN; ++a) {
                const float ma = ar[a];
#pragma unroll
                for (int j = 0; j < TEN; ++j) c[j] = fmaf(ma, src[120 + a * 12 + j], c[j]);
            }
#pragma unroll
            for (int j = 0; j < TEN; ++j) lds[5760 + r * 12 + j] = c[j];
        }
        __syncthreads();
        if (tid < TEN) {
            const int r = tid;
            float c[TEN] = {0, 0, 0, 0, 0, 0, 0, 0, 0, 0};
#pragma unroll
            for (int a = 0; a < TEN; ++a) {
                const float ma = lds[5760 + r * 12 + a];
#pragma unroll
                for (int j = 0; j < TEN; ++j) c[j] = fmaf(ma, src[240 + a * 12 + j], c[j]);
            }
            float* dr = outBlk + (size_t)blockIdx.x * 100 + r * TEN;
#pragma unroll
            for (int j = 0; j < TEN; ++j) dr[j] = c[j];
        }
    }
}

// ---------------------------------------------------------------------------
// tree64 helper for the final kernel (row-major slots, stride 120).
// Quad row partition {0,1,2},{3,4,5},{6,7,(dup)},{8,9,(dup)}.
// ---------------------------------------------------------------------------
__device__ __forceinline__ void tree64(float* lds, int tid)
{
    const int q     = tid >> 2;
    const int sub   = tid & 3;
    const int rbase = (sub == 3) ? 8 : sub * 3;
    const int r0 = rbase, r1 = rbase + 1;
    const int r2 = (rbase + 2 > 9) ? 9 : rbase + 2;
    const bool w2 = (sub < 2);

    for (int np = 32; np >= 1; np >>= 1) {
        float c[3][TEN];
        if (q < np) {
            const float* A = lds + (2 * q) * 120;
            const float* B = lds + (2 * q + 1) * 120;
            float ar[3][TEN];
#pragma unroll
            for (int t = 0; t < 3; ++t) {
                const int rt = (t == 0) ? r0 : (t == 1) ? r1 : r2;
                const float4 a0 = reinterpret_cast<const float4*>(A + rt * 12)[0];
                const float4 a1 = reinterpret_cast<const float4*>(A + rt * 12)[1];
                const float2 a2 = reinterpret_cast<const float2*>(A + rt * 12 + 8)[0];
                ar[t][0]=a0.x; ar[t][1]=a0.y; ar[t][2]=a0.z; ar[t][3]=a0.w;
                ar[t][4]=a1.x; ar[t][5]=a1.y; ar[t][6]=a1.z; ar[t][7]=a1.w;
                ar[t][8]=a2.x; ar[t][9]=a2.y;
#pragma unroll
                for (int j = 0; j < TEN; ++j) c[t][j] = 0.0f;
            }
#pragma unroll
            for (int a = 0; a < TEN; ++a) {
                const float4 b0 = reinterpret_cast<const float4*>(B + a * 12)[0];
                const float4 b1 = reinterpret_cast<const float4*>(B + a * 12)[1];
                const float2 b2 = reinterpret_cast<const float2*>(B + a * 12 + 8)[0];
                const float br[TEN] = {b0.x,b0.y,b0.z,b0.w,b1.x,b1.y,b1.z,b1.w,b2.x,b2.y};
#pragma unroll
                for (int t = 0; t < 3; ++t) {
                    const float ma = ar[t][a];
#pragma unroll
                    for (int j = 0; j < TEN; ++j) c[t][j] = fmaf(ma, br[j], c[t][j]);
                }
            }
        }
        __syncthreads();
        if (q < np) {
            float* C = lds + q * 120;
#pragma unroll
            for (int t = 0; t < 3; ++t) {
                const int rt = (t == 0) ? r0 : (t == 1) ? r1 : r2;
                if (t < 2 || w2) {
                    float* cr = C + rt * 12;
                    reinterpret_cast<float4*>(cr)[0] = make_float4(c[t][0], c[t][1], c[t][2], c[t][3]);
                    reinterpret_cast<float4*>(cr)[1] = make_float4(c[t][4], c[t][5], c[t][6], c[t][7]);
                    reinterpret_cast<float2*>(cr + 8)[0] = make_float2(c[t][8], c[t][9]);
                }
            }
        }
        __syncthreads();
    }
}

// ---------------------------------------------------------------------------
// Final: one block. 64 quads chain 4 consecutive block-matrices (256 -> 64),
// tree64 -> 1, then apply start/accept.
// ---------------------------------------------------------------------------
__global__ void automaton_final(const float* __restrict__ blkM,
                                const float* __restrict__ start,
                                const float* __restrict__ acc,
                                float* __restrict__ outv)
{
    __shared__ __align__(16) float lds[7680];
    __shared__ float sv[TEN];
    const int tid = threadIdx.x;
    const int q   = tid >> 2;
    const int sub = tid & 3;
    const int rbase = (sub == 3) ? 8 : sub * 3;
    const int rr0 = rbase, rr1 = rbase + 1;
    const int rr2 = (rbase + 2 > 9) ? 9 : rbase + 2;
    const bool w2 = (sub < 2);

    float a[3][TEN];
    {
        const int rr[3] = {rr0, rr1, rr2};
        const float* A0 = blkM + (size_t)(4 * q) * 100;
#pragma unroll
        for (int t = 0; t < 3; ++t) {
            const float2* pp = reinterpret_cast<const float2*>(A0 + rr[t] * TEN);
            const float2 a0 = pp[0], a1 = pp[1], a2 = pp[2], a3 = pp[3], a4 = pp[4];
            a[t][0]=a0.x; a[t][1]=a0.y; a[t][2]=a1.x; a[t][3]=a1.y; a[t][4]=a2.x;
            a[t][5]=a2.y; a[t][6]=a3.x; a[t][7]=a3.y; a[t][8]=a4.x; a[t][9]=a4.y;
        }
    }
#pragma unroll 1
    for (int i = 1; i < 4; ++i) {
        const float* B = blkM + (size_t)(4 * q + i) * 100;
        float c[3][TEN];
#pragma unroll
        for (int t = 0; t < 3; ++t)
#pragma unroll
            for (int j = 0; j < TEN; ++j) c[t][j] = 0.0f;
#pragma unroll
        for (int aa = 0; aa < TEN; ++aa) {
            const float2* br = reinterpret_cast<const float2*>(B + aa * TEN);
            const float2 b0 = br[0], b1 = br[1], b2 = br[2], b3 = br[3], b4 = br[4];
            const float bv[TEN] = {b0.x,b0.y,b1.x,b1.y,b2.x,b2.y,b3.x,b3.y,b4.x,b4.y};
#pragma unroll
            for (int t = 0; t < 3; ++t) {
                const float ma = a[t][aa];
#pragma unroll
                for (int j = 0; j < TEN; ++j) c[t][j] = fmaf(ma, bv[j], c[t][j]);
            }
        }
#pragma unroll
        for (int t = 0; t < 3; ++t)
#pragma unroll
            for (int j = 0; j < TEN; ++j) a[t][j] = c[t][j];
    }
    {
        float* dst = lds + q * 120;
#pragma unroll
        for (int t = 0; t < 3; ++t) {
            const int rt = (t == 0) ? rr0 : (t == 1) ? rr1 : rr2;
            if (t < 2 || w2) {
                float* dr = dst + rt * 12;
                reinterpret_cast<float4*>(dr)[0] = make_float4(a[t][0], a[t][1], a[t][2], a[t][3]);
                reinterpret_cast<float4*>(dr)[1] = make_float4(a[t][4], a[t][5], a[t][6], a[t][7]);
                reinterpret_cast<float2*>(dr + 8)[0] = make_float2(a[t][8], a[t][9]);
            }
        }
    }
    __syncthreads();
    tree64(lds, tid);

    if (tid < TEN) {
        const int j = tid;
        float v = 0.0f;
#pragma unroll
        for (int r = 0; r < TEN; ++r) v = fmaf(start[r], lds[r * 12 + j], v);
        sv[j] = v;
    }
    __syncthreads();
    if (tid == 0) {
        float o0 = 0.0f, o1 = 0.0f;
#pragma unroll
        for (int j = 0; j < TEN; ++j) {
            o0 = fmaf(sv[j], acc[2 * j + 0], o0);
            o1 = fmaf(sv[j], acc[2 * j + 1], o1);
        }
        outv[0] = o0;
        outv[1] = o1;
    }
}

extern "C" void kernel_launch(void* const* d_in, const int* in_sizes, int n_in,
                              void* d_out, int out_size, void* d_ws, size_t ws_size,
                              hipStream_t stream)
{
    const float* x     = (const float*)d_in[0];
    const float* P     = (const float*)d_in[1];
    const float* start = (const float*)d_in[2];
    const float* acc   = (const float*)d_in[3];
    float* out         = (float*)d_out;

    const long long T = (long long)in_sizes[0] / TEN;  // 2,097,152 steps
    const int C = 12288;                               // 48 chunks x 256 blocks

    float* blkM = (float*)d_ws;                        // [256][10][10]

    automaton_chunks<<<256, 256, 0, stream>>>(x, P, blkM, T, C);
    automaton_final<<<1, 256, 0, stream>>>(blkM, start, acc, out);
}